// Round 4
// baseline (382.131 us; speedup 1.0000x reference)
//
#include <hip/hip_runtime.h>

#define B_  32
#define T_  256
#define F_  64
#define C_  16
#define CO_ 16
#define P_  64
#define S_  32
#define K_  4
#define FC_ 1024   // F*C
#define OUTC 96
#define TT  8      // t-tile per block

// v4: no x LDS staging at all -- x is read through L1/L2 (wave-uniform
// broadcast loads in phase 1, 16-lane broadcast in conv). LDS shrinks
// 75.7 KB -> 26 KB, occupancy 2 -> up to 4 blocks/CU (wave limit).
//  block = (b, 8-wide t tile, ALL f), 512 threads, 1024 blocks.
//  LDS layout (float lds[6656], 26 KB):
//    [0..4096)    phase-1 point-GEMM partials (8 ks x 8 rows x 64 p)
//    [0..3072) / [3072..6144)  double-buffered output staging (phase 2)
//    [6144..6656) pv = relu(point_out) rows (never overwritten)
//  Dump loop: ONE lgkm-only barrier per t (double buffer), stores never
//  drained in-loop. Store pattern identical to v1 (monolithic 12 KB dumps;
//  v2 proved strided stores amplify WRITE_SIZE 2.5x).
__global__ __launch_bounds__(512, 4) void tpc_fused(
    const float* __restrict__ x, const float* __restrict__ stat,
    const float* __restrict__ cw, const float* __restrict__ cb,
    const float* __restrict__ Wp, const float* __restrict__ bp,
    float* __restrict__ out)
{
    __shared__ __align__(16) float lds[6656];   // 26 KB
    float* part = lds;            // phase-1 partials
    float* pv   = lds + 6144;     // relu'd point rows

    int tid = threadIdx.x;
    int blk = blockIdx.x;      // 0..1023
    int b  = blk >> 5;
    int t0 = (blk & 31) * TT;

    const float* xrow0 = x + ((size_t)(b * T_ + t0)) * FC_;   // row t0

    // ---- phase 1: point GEMM partials; wave = one 128-wide k slice ----
    // x reads are wave-uniform (address depends on ks=waveid only) ->
    // single broadcast fetch per instruction, L1/L2 served.
    {
        int p  = tid & 63;
        int ks = tid >> 6;                 // 0..7
        float acc[TT];
        #pragma unroll
        for (int r = 0; r < TT; ++r) acc[r] = 0.f;
        int k0base = ks * 128;
        for (int kk = 0; kk < 128; kk += 4) {
            int k0 = k0base + kk;
            float w0 = Wp[(size_t)(k0 + 0) * P_ + p];
            float w1 = Wp[(size_t)(k0 + 1) * P_ + p];
            float w2 = Wp[(size_t)(k0 + 2) * P_ + p];
            float w3 = Wp[(size_t)(k0 + 3) * P_ + p];
            #pragma unroll
            for (int r = 0; r < TT; ++r) {
                float4 xv = *(const float4*)(xrow0 + r * FC_ + k0);
                acc[r] += xv.x * w0 + xv.y * w1 + xv.z * w2 + xv.w * w3;
            }
        }
        #pragma unroll
        for (int r = 0; r < TT; ++r)
            part[(ks * TT + r) * P_ + p] = acc[r];
    }
    __syncthreads();

    // ---- phase 1b: reduce + bias + static; relu -> pv (disjoint region,
    //      no extra barrier needed before the write) ----
    {
        int p = tid & 63;
        int r = tid >> 6;                  // row 0..7
        float s = bp[p];
        const float* wst = Wp + (size_t)FC_ * P_;
        #pragma unroll 8
        for (int si = 0; si < S_; ++si)
            s += stat[b * S_ + si] * wst[si * P_ + p];
        #pragma unroll
        for (int ks = 0; ks < 8; ++ks)
            s += part[(ks * TT + r) * P_ + p];
        pv[r * P_ + p] = fmaxf(s, 0.f);
    }
    __syncthreads();   // pv visible; all partial reads done before staging reuse

    // ---- phase 2: conv (global-x) + concat fusion, staged full-line dumps ----
    int co = tid & 15;
    int fh = tid >> 4;                     // 0..31 (local f within half)
    int p  = tid & 63;
    int fg = tid >> 6;                     // 0..7

    int bufsel = 0;
    #pragma unroll
    for (int half = 0; half < 2; ++half) {
        int f = half * 32 + fh;
        // conv weights for (f, co): 64 floats
        float w[64];
        const float4* wg = (const float4*)(cw + ((size_t)(f * CO_ + co)) * (C_ * K_));
        #pragma unroll
        for (int j = 0; j < 16; ++j) {
            float4 t4 = wg[j];
            w[4 * j + 0] = t4.x; w[4 * j + 1] = t4.y;
            w[4 * j + 2] = t4.z; w[4 * j + 3] = t4.w;
        }
        float bias = cb[f * CO_ + co];

        for (int tl = 0; tl < TT; ++tl) {
            float* st = lds + bufsel * 3072;
            // conv result from global x (uniform branch on causal pad)
            float temp = bias;
            #pragma unroll
            for (int k = 0; k < K_; ++k) {
                int tg = t0 + tl + 2 * k - 6;
                if (tg >= 0) {
                    const float* sp = x + ((size_t)(b * T_ + tg)) * FC_ + f * C_;
                    #pragma unroll
                    for (int c4 = 0; c4 < 4; ++c4) {
                        float4 xv = *(const float4*)(sp + c4 * 4);
                        temp += xv.x * w[(c4 * 4 + 0) * 4 + k];
                        temp += xv.y * w[(c4 * 4 + 1) * 4 + k];
                        temp += xv.z * w[(c4 * 4 + 2) * 4 + k];
                        temp += xv.w * w[(c4 * 4 + 3) * 4 + k];
                    }
                }
            }
            st[fh * OUTC + 16 + co] = fmaxf(temp, 0.f);
            // x passthrough (contiguous wave read from global)
            st[fh * OUTC + co] =
                fmaxf(x[((size_t)(b * T_ + t0 + tl)) * FC_ + f * C_ + co], 0.f);
            // point broadcast (reads pv region: disjoint from staging)
            float pvv = pv[tl * P_ + p];
            #pragma unroll
            for (int fo = 0; fo < 4; ++fo)
                st[(fo * 8 + fg) * OUTC + 32 + p] = pvv;

            // single barrier per t: staging visible; prev dump reads of this
            // buffer were drained by each wave's own lgkmcnt at the previous
            // barrier (double buffer) -- stores never drained here.
            asm volatile("s_waitcnt lgkmcnt(0)" ::: "memory");
            __builtin_amdgcn_sched_barrier(0);
            __builtin_amdgcn_s_barrier();
            __builtin_amdgcn_sched_barrier(0);

            // dump 12 KB contiguous (full 128B lines, v1's proven pattern)
            {
                const float4* src = (const float4*)st;
                float4* dst = (float4*)(out + ((size_t)(b * T_ + t0 + tl)) * F_ * OUTC
                                        + half * 3072);
                dst[tid] = src[tid];
                if (tid < 256) dst[512 + tid] = src[512 + tid];
            }
            bufsel ^= 1;
        }
    }
}

extern "C" void kernel_launch(void* const* d_in, const int* in_sizes, int n_in,
                              void* d_out, int out_size, void* d_ws, size_t ws_size,
                              hipStream_t stream) {
    const float* x    = (const float*)d_in[0];
    const float* stat = (const float*)d_in[1];
    const float* cw   = (const float*)d_in[2];
    const float* cb   = (const float*)d_in[3];
    const float* Wp   = (const float*)d_in[4];
    const float* bp   = (const float*)d_in[5];
    float* out = (float*)d_out;

    tpc_fused<<<1024, 512, 0, stream>>>(x, stat, cw, cb, Wp, bp, out);
}

// Round 5
// 329.277 us; speedup vs baseline: 1.1605x; 1.1605x over previous
//
#include <hip/hip_runtime.h>

#define B_  32
#define T_  256
#define F_  64
#define C_  16
#define CO_ 16
#define P_  64
#define S_  32
#define K_  4
#define FC_ 1024   // F*C
#define OUTC 96
#define TT  8      // t-tile per block (kernel B)
#define NS  14     // TT + 6 halo slices
#define TA  16     // t-rows per block (kernel A)

// v5: two-kernel split. A = point GEMM -> pv workspace (v1 phase1/1b math,
// bit-identical order). B = v3 minus phase1: xs staging + conv + monolithic
// full-line dumps (proven store pattern), pv hoisted to registers.
// Rationale: v1's 108us = ~45us traffic floor + intra-block phase
// serialization; the GEMM shares nothing with the store stream, so unchain it.

// ---------------- kernel A: point GEMM ----------------
__global__ __launch_bounds__(512, 4) void tpc_point(
    const float* __restrict__ x, const float* __restrict__ stat,
    const float* __restrict__ Wp, const float* __restrict__ bp,
    float* __restrict__ pvg)
{
    __shared__ float part[8 * TA * P_];    // 32 KB: ks x row x p

    int tid = threadIdx.x;
    int blk = blockIdx.x;          // 0..511
    int b  = blk >> 4;
    int t0 = (blk & 15) * TA;

    int p  = tid & 63;
    int ks = tid >> 6;             // 0..7, k-slice of 128
    const float* xbase = x + ((size_t)(b * T_ + t0)) * FC_;

    float acc[TA];
    #pragma unroll
    for (int r = 0; r < TA; ++r) acc[r] = 0.f;

    int k0b = ks * 128;
    for (int kk = 0; kk < 128; kk += 4) {
        int k0 = k0b + kk;
        float w0 = Wp[(size_t)(k0 + 0) * P_ + p];
        float w1 = Wp[(size_t)(k0 + 1) * P_ + p];
        float w2 = Wp[(size_t)(k0 + 2) * P_ + p];
        float w3 = Wp[(size_t)(k0 + 3) * P_ + p];
        #pragma unroll
        for (int r = 0; r < TA; ++r) {
            float4 xv = *(const float4*)(xbase + r * FC_ + k0);
            acc[r] += xv.x * w0 + xv.y * w1 + xv.z * w2 + xv.w * w3;
        }
    }
    #pragma unroll
    for (int r = 0; r < TA; ++r)
        part[(ks * TA + r) * P_ + p] = acc[r];
    __syncthreads();

    // reduce + bias + static -> relu -> pv   (v1 order: bp, +static, +parts)
    {
        int rr = tid >> 6;                 // 0..7; rows rr and rr+8
        float s0 = bp[p];
        const float* wst = Wp + (size_t)FC_ * P_;
        #pragma unroll 8
        for (int si = 0; si < S_; ++si)
            s0 += stat[b * S_ + si] * wst[si * P_ + p];
        #pragma unroll
        for (int h = 0; h < 2; ++h) {
            int r = rr + h * 8;
            float s = s0;
            #pragma unroll
            for (int k2 = 0; k2 < 8; ++k2)
                s += part[(k2 * TA + r) * P_ + p];
            pvg[((size_t)(b * T_ + t0 + r)) * P_ + p] = fmaxf(s, 0.f);
        }
    }
}

// ---------------- kernel B: conv + concat + store ----------------
__global__ __launch_bounds__(512, 4) void tpc_fuse(
    const float* __restrict__ x, const float* __restrict__ cw,
    const float* __restrict__ cb, const float* __restrict__ pvg,
    float* __restrict__ out)
{
    __shared__ __align__(16) float xs[NS * FC_];   // 57.3 KB
    __shared__ __align__(16) float u[3072];        // 12 KB staging

    int tid = threadIdx.x;
    int blk = blockIdx.x;      // 0..1023
    int b  = blk >> 5;
    int t0 = (blk & 31) * TT;

    // ---- stage x[t0-6 .. t0+TT-1, :, :] into LDS (zero left pad) ----
    #pragma unroll
    for (int it = 0; it < 7; ++it) {
        int v = it * 512 + tid;            // float4 id, NS*256 = 3584 total
        int slice = v >> 8;
        int pos   = v & 255;
        int tg = t0 - 6 + slice;
        float4 val = make_float4(0.f, 0.f, 0.f, 0.f);
        if (tg >= 0)
            val = *(const float4*)(x + ((size_t)(b * T_ + tg)) * FC_ + pos * 4);
        *(float4*)(xs + slice * FC_ + pos * 4) = val;
    }

    // ---- hoist pv rows into registers (pipelined global loads) ----
    int p  = tid & 63;
    float pvr[TT];
    #pragma unroll
    for (int tl = 0; tl < TT; ++tl)
        pvr[tl] = pvg[((size_t)(b * T_ + t0 + tl)) * P_ + p];

    __syncthreads();

    // ---- phase 2 (v3 verbatim, pvv from registers) ----
    int co = tid & 15;
    int fh = tid >> 4;                     // 0..31 (local f within half)
    int fg = tid >> 6;                     // 0..7

    #pragma unroll
    for (int half = 0; half < 2; ++half) {
        int f = half * 32 + fh;
        float w[64];
        const float4* wg = (const float4*)(cw + ((size_t)(f * CO_ + co)) * (C_ * K_));
        #pragma unroll
        for (int j = 0; j < 16; ++j) {
            float4 t4 = wg[j];
            w[4 * j + 0] = t4.x; w[4 * j + 1] = t4.y;
            w[4 * j + 2] = t4.z; w[4 * j + 3] = t4.w;
        }
        float bias = cb[f * CO_ + co];

        for (int tl = 0; tl < TT; ++tl) {
            float temp = bias;
            #pragma unroll
            for (int k = 0; k < K_; ++k) {
                const float* sp = xs + (tl + 2 * k) * FC_ + f * C_;
                #pragma unroll
                for (int c4 = 0; c4 < 4; ++c4) {
                    float4 xv = *(const float4*)(sp + c4 * 4);
                    temp += xv.x * w[(c4 * 4 + 0) * 4 + k];
                    temp += xv.y * w[(c4 * 4 + 1) * 4 + k];
                    temp += xv.z * w[(c4 * 4 + 2) * 4 + k];
                    temp += xv.w * w[(c4 * 4 + 3) * 4 + k];
                }
            }
            u[fh * OUTC + 16 + co] = fmaxf(temp, 0.f);
            u[fh * OUTC + co] = fmaxf(xs[(tl + 6) * FC_ + f * C_ + co], 0.f);
            float pvv = pvr[tl];
            #pragma unroll
            for (int fo = 0; fo < 4; ++fo)
                u[(fo * 8 + fg) * OUTC + 32 + p] = pvv;

            asm volatile("s_waitcnt lgkmcnt(0)" ::: "memory");
            __builtin_amdgcn_sched_barrier(0);
            __builtin_amdgcn_s_barrier();
            __builtin_amdgcn_sched_barrier(0);

            // dump 12 KB contiguous (full 128B lines, proven pattern)
            {
                const float4* src = (const float4*)u;
                float4* dst = (float4*)(out + ((size_t)(b * T_ + t0 + tl)) * F_ * OUTC
                                        + half * 3072);
                dst[tid] = src[tid];
                if (tid < 256) dst[512 + tid] = src[512 + tid];
            }

            asm volatile("s_waitcnt lgkmcnt(0)" ::: "memory");
            __builtin_amdgcn_sched_barrier(0);
            __builtin_amdgcn_s_barrier();
            __builtin_amdgcn_sched_barrier(0);
        }
    }
}

extern "C" void kernel_launch(void* const* d_in, const int* in_sizes, int n_in,
                              void* d_out, int out_size, void* d_ws, size_t ws_size,
                              hipStream_t stream) {
    const float* x    = (const float*)d_in[0];
    const float* stat = (const float*)d_in[1];
    const float* cw   = (const float*)d_in[2];
    const float* cb   = (const float*)d_in[3];
    const float* Wp   = (const float*)d_in[4];
    const float* bp   = (const float*)d_in[5];
    float* out = (float*)d_out;
    float* pvg = (float*)d_ws;   // B*T*P*4 = 2 MB intermediate

    tpc_point<<<512, 512, 0, stream>>>(x, stat, Wp, bp, pvg);
    tpc_fuse<<<1024, 512, 0, stream>>>(x, cw, cb, pvg, out);
}

// Round 6
// 273.710 us; speedup vs baseline: 1.3961x; 1.2030x over previous
//
#include <hip/hip_runtime.h>

#define B_  32
#define T_  256
#define F_  64
#define C_  16
#define CO_ 16
#define P_  64
#define S_  32
#define K_  4
#define FC_ 1024   // F*C
#define OUTC 96
#define TT  8      // t-tile per block
#define NS  14     // TT + 6 halo slices (dilation*(K-1) = 6)

// v6: register-resident outputs + wide monolithic dumps.
// Evidence ledger: monolithic dumps mandatory (v2: RFO + 2.5x WRITE);
// bulk xs staging mandatory (v4: 207us latency-bound); GEMM off critical
// path (v5: split saved nothing in B). Bottleneck = phase-2's 32
// barrier-separated micro-steps. v6 computes conv+passthrough+point into
// registers with NO barriers, then runs 8 pure dump iterations (24 KB
// full-t-row monolithic stores, 1 lgkm-only barrier each, double-buffered
// staging ALIASED over the dead xs region -> LDS stays 74 KB, 2 blocks/CU).
__global__ __launch_bounds__(512, 4) void tpc_fused(
    const float* __restrict__ x, const float* __restrict__ stat,
    const float* __restrict__ cw, const float* __restrict__ cb,
    const float* __restrict__ Wp, const float* __restrict__ bp,
    float* __restrict__ out)
{
    __shared__ __align__(16) float lds[18944];   // 74 KB total
    float* xs   = lds;            // [0 .. 14336)  x slices (dead after conv)
    float* part = lds + 14336;    // [14336 .. 18432) phase-1 partials
    float* pv   = lds + 18432;    // [18432 .. 18944) relu'd point rows
    // staging: stg[i] = lds + i*6144, aliases xs after it is dead

    int tid = threadIdx.x;
    int blk = blockIdx.x;      // 0..1023
    int b  = blk >> 5;
    int t0 = (blk & 31) * TT;

    // ---- stage x[t0-6 .. t0+TT-1, :, :] into LDS (zero left pad) ----
    #pragma unroll
    for (int it = 0; it < 7; ++it) {
        int v = it * 512 + tid;            // float4 id, NS*256 = 3584 total
        int slice = v >> 8;
        int pos   = v & 255;
        int tg = t0 - 6 + slice;
        float4 val = make_float4(0.f, 0.f, 0.f, 0.f);
        if (tg >= 0)
            val = *(const float4*)(x + ((size_t)(b * T_ + tg)) * FC_ + pos * 4);
        *(float4*)(xs + slice * FC_ + pos * 4) = val;
    }
    __syncthreads();

    // ---- phase 1: point GEMM partials; wave = one 128-wide k slice ----
    {
        int p  = tid & 63;
        int ks = tid >> 6;                 // 0..7
        float acc[TT];
        #pragma unroll
        for (int r = 0; r < TT; ++r) acc[r] = 0.f;
        int k0base = ks * 128;
        for (int kk = 0; kk < 128; kk += 4) {
            int k0 = k0base + kk;
            float w0 = Wp[(size_t)(k0 + 0) * P_ + p];
            float w1 = Wp[(size_t)(k0 + 1) * P_ + p];
            float w2 = Wp[(size_t)(k0 + 2) * P_ + p];
            float w3 = Wp[(size_t)(k0 + 3) * P_ + p];
            #pragma unroll
            for (int r = 0; r < TT; ++r) {
                float4 xv = *(const float4*)(xs + (6 + r) * FC_ + k0);
                acc[r] += xv.x * w0 + xv.y * w1 + xv.z * w2 + xv.w * w3;
            }
        }
        #pragma unroll
        for (int r = 0; r < TT; ++r)
            part[(ks * TT + r) * P_ + p] = acc[r];
    }
    __syncthreads();

    int p  = tid & 63;
    int co = tid & 15;
    int fh = tid >> 4;                     // 0..31 (local f within half)
    int fg = tid >> 6;                     // 0..7

    // ---- phase 1b: reduce + bias + static; relu -> pv (disjoint region) ----
    {
        int r = tid >> 6;                  // row 0..7
        float s = bp[p];
        const float* wst = Wp + (size_t)FC_ * P_;
        #pragma unroll 8
        for (int si = 0; si < S_; ++si)
            s += stat[b * S_ + si] * wst[si * P_ + p];
        #pragma unroll
        for (int ks = 0; ks < 8; ++ks)
            s += part[(ks * TT + r) * P_ + p];
        pv[r * P_ + p] = fmaxf(s, 0.f);
    }

    // ---- conv + x passthrough -> registers (xs reads, no barriers) ----
    float cv[2][TT], px[2][TT];
    #pragma unroll
    for (int half = 0; half < 2; ++half) {
        int f = half * 32 + fh;
        float w[64];
        const float4* wg = (const float4*)(cw + ((size_t)(f * CO_ + co)) * (C_ * K_));
        #pragma unroll
        for (int j = 0; j < 16; ++j) {
            float4 t4 = wg[j];
            w[4 * j + 0] = t4.x; w[4 * j + 1] = t4.y;
            w[4 * j + 2] = t4.z; w[4 * j + 3] = t4.w;
        }
        float bias = cb[f * CO_ + co];
        #pragma unroll
        for (int tl = 0; tl < TT; ++tl) {
            float temp = bias;
            #pragma unroll
            for (int k = 0; k < K_; ++k) {
                const float* sp = xs + (tl + 2 * k) * FC_ + f * C_;
                #pragma unroll
                for (int c4 = 0; c4 < 4; ++c4) {
                    float4 xv = *(const float4*)(sp + c4 * 4);
                    temp += xv.x * w[(c4 * 4 + 0) * 4 + k];
                    temp += xv.y * w[(c4 * 4 + 1) * 4 + k];
                    temp += xv.z * w[(c4 * 4 + 2) * 4 + k];
                    temp += xv.w * w[(c4 * 4 + 3) * 4 + k];
                }
            }
            cv[half][tl] = fmaxf(temp, 0.f);
            px[half][tl] = fmaxf(xs[(tl + 6) * FC_ + f * C_ + co], 0.f);
        }
    }
    __syncthreads();   // all xs reads drained (xs now dead); pv visible

    // hoist pv rows for this thread's p
    float pvr[TT];
    #pragma unroll
    for (int tl = 0; tl < TT; ++tl)
        pvr[tl] = pv[tl * P_ + p];

    // ---- pure dump loop: 8 iterations, 24 KB monolithic stores ----
    for (int tl = 0; tl < TT; ++tl) {
        float* st = lds + (tl & 1) * 6144;   // aliases dead xs region
        // stage full t-row [f=0..63][96] from registers
        st[fh * OUTC + co]               = px[0][tl];
        st[fh * OUTC + 16 + co]          = cv[0][tl];
        st[(fh + 32) * OUTC + co]        = px[1][tl];
        st[(fh + 32) * OUTC + 16 + co]   = cv[1][tl];
        float pvv = pvr[tl];
        #pragma unroll
        for (int fo = 0; fo < 8; ++fo)
            st[(fo * 8 + fg) * OUTC + 32 + p] = pvv;

        // single lgkm-only barrier (double buffer; prev readers of this buffer
        // drained their reads at the previous barrier; stores never drained)
        asm volatile("s_waitcnt lgkmcnt(0)" ::: "memory");
        __builtin_amdgcn_sched_barrier(0);
        __builtin_amdgcn_s_barrier();
        __builtin_amdgcn_sched_barrier(0);

        // dump 24 KB contiguous (one full t row, full 128B lines)
        const float4* src = (const float4*)st;
        float4* dst = (float4*)(out + ((size_t)(b * T_ + t0 + tl)) * F_ * OUTC);
        dst[tid]        = src[tid];
        dst[512 + tid]  = src[512 + tid];
        dst[1024 + tid] = src[1024 + tid];
    }
}

extern "C" void kernel_launch(void* const* d_in, const int* in_sizes, int n_in,
                              void* d_out, int out_size, void* d_ws, size_t ws_size,
                              hipStream_t stream) {
    const float* x    = (const float*)d_in[0];
    const float* stat = (const float*)d_in[1];
    const float* cw   = (const float*)d_in[2];
    const float* cb   = (const float*)d_in[3];
    const float* Wp   = (const float*)d_in[4];
    const float* bp   = (const float*)d_in[5];
    float* out = (float*)d_out;

    tpc_fused<<<1024, 512, 0, stream>>>(x, stat, cw, cb, Wp, bp, out);
}